// Round 5
// baseline (12730.612 us; speedup 1.0000x reference)
//
#include <hip/hip_runtime.h>

// LSTM_65859028517106 — round 5: deep (no-reuse) h ring, agent-scope (sc0)
// L2-cached h reads so each XCD's L2 serves the 32-way broadcast; system-scope
// (sc0 sc1) h writes + flags. Fallback to r4 shallow kernel if ws too small.

typedef short s16x8 __attribute__((ext_vector_type(8)));
typedef float f32x4 __attribute__((ext_vector_type(4)));

#define NB   128
#define TT   1024
#define HID2 512
#define RING 8
#define NBH  (NB * HID2)
#define STAGE_OFF (128 * 1024)

__device__ __forceinline__ unsigned short f2bf(float f) {
  union { float f; unsigned int u; } c; c.f = f;
  return (unsigned short)((c.u + 0x7fffu + ((c.u >> 16) & 1u)) >> 16);
}
__device__ __forceinline__ float sigm(float x) { return 1.0f / (1.0f + __expf(-x)); }
__device__ __forceinline__ float tanhfast(float x) {
  x = fminf(fmaxf(x, -15.0f), 15.0f);
  const float e = __expf(2.0f * x);
  return (e - 1.0f) / (e + 1.0f);
}

__global__ void convW(const float* __restrict__ Wih, const float* __restrict__ Whh,
                      const float* __restrict__ bih, const float* __restrict__ bhh,
                      unsigned short* __restrict__ Wd, float* __restrict__ biasd,
                      const int Kih, const int Khh) {
  const int K = Kih + Khh;
  const int total = 2048 * K;
  for (int idx = blockIdx.x * blockDim.x + threadIdx.x; idx < total;
       idx += gridDim.x * blockDim.x) {
    const int rp = idx / K;
    const int cc = idx - rp * K;
    const int g = rp & 3, u = rp >> 2;
    const int ro = g * 512 + u;
    const float v = (cc < Kih) ? Wih[ro * Kih + cc] : Whh[ro * Khh + (cc - Kih)];
    Wd[idx] = f2bf(v);
    if (cc == 0) biasd[rp] = bih[ro] + bhh[ro];
  }
}

__global__ void convO(const float* __restrict__ Wout, unsigned short* __restrict__ Wd) {
  for (int idx = blockIdx.x * blockDim.x + threadIdx.x; idx < 128 * 512;
       idx += gridDim.x * blockDim.x)
    Wd[idx] = f2bf(Wout[idx]);
}

// system-scope (IC-coherent, bypass) ops
#define GLD2(D0, D1, B0, B1, OFF)                                         \
  asm volatile("global_load_dwordx4 %0, %2, off offset:" OFF " sc0 sc1\n\t" \
               "global_load_dwordx4 %1, %3, off offset:" OFF " sc0 sc1"   \
               : "=v"(D0), "=v"(D1) : "v"(B0), "v"(B1));
#define GLD1(D, B, OFF)                                                   \
  asm volatile("global_load_dwordx4 %0, %1, off offset:" OFF " sc0 sc1"   \
               : "=v"(D) : "v"(B));
// agent-scope (L2-cached, L1-bypass) loads — deep ring only
#define GLD2A(D0, D1, B0, B1, OFF)                                        \
  asm volatile("global_load_dwordx4 %0, %2, off offset:" OFF " sc0\n\t"   \
               "global_load_dwordx4 %1, %3, off offset:" OFF " sc0"       \
               : "=v"(D0), "=v"(D1) : "v"(B0), "v"(B1));
#define GLD1A(D, B, OFF)                                                  \
  asm volatile("global_load_dwordx4 %0, %1, off offset:" OFF " sc0"       \
               : "=v"(D) : "v"(B));
#define BWAIT(D0, D1, VM)                                                 \
  asm volatile("s_waitcnt vmcnt(" VM ")" : "+v"(D0), "+v"(D1)::"memory");
#define BW1(D, VM)                                                        \
  asm volatile("s_waitcnt vmcnt(" VM ")" : "+v"(D)::"memory");

#define MFM(A, B, C) __builtin_amdgcn_mfma_f32_16x16x32_bf16(A, B, C, 0, 0, 0)
#define LDSA(MFi, AK) \
  (*reinterpret_cast<const s16x8*>(smem + (((MFi) * nkit + (AK)) << 10) + lane * 16))
#define CONSUME(SLOT, AK, VM)                                                   \
  {                                                                             \
    BWAIT(bq[SLOT][0], bq[SLOT][1], VM);                                        \
    const s16x8 af0 = LDSA(0, AK), af1 = LDSA(1, AK), af2 = LDSA(2, AK),        \
                af3 = LDSA(3, AK);                                              \
    acc[0][0] = MFM(af0, bq[SLOT][0], acc[0][0]);                               \
    acc[0][1] = MFM(af0, bq[SLOT][1], acc[0][1]);                               \
    acc[1][0] = MFM(af1, bq[SLOT][0], acc[1][0]);                               \
    acc[1][1] = MFM(af1, bq[SLOT][1], acc[1][1]);                               \
    acc[2][0] = MFM(af2, bq[SLOT][0], acc[2][0]);                               \
    acc[2][1] = MFM(af2, bq[SLOT][1], acc[2][1]);                               \
    acc[3][0] = MFM(af3, bq[SLOT][0], acc[3][0]);                               \
    acc[3][1] = MFM(af3, bq[SLOT][1], acc[3][1]);                               \
  }

#define POLLDEF                                                            \
  auto pollAll = [&](const unsigned int* pa) {                             \
    for (;;) {                                                             \
      unsigned int v;                                                      \
      asm volatile("global_load_dword %0, %1, off sc0 sc1\n\ts_waitcnt vmcnt(0)" \
                   : "=v"(v) : "v"(pa) : "memory");                        \
      if (__all(v != 0)) break;                                            \
      __builtin_amdgcn_s_sleep(1);                                         \
    }                                                                      \
  };
#define FLG(L, T) (flags + ((size_t)((L) * TT + (T)) << 5))

// ==================== DEEP kernel (no-reuse ring) ====================
__global__ __launch_bounds__(256, 1) void lstm_deep(
    const float* __restrict__ x,
    const unsigned short* __restrict__ W0, const unsigned short* __restrict__ W1,
    const unsigned short* __restrict__ W2, const unsigned short* __restrict__ W3,
    const unsigned short* __restrict__ W4,
    const unsigned short* __restrict__ Woutb,
    const float* __restrict__ bias,
    unsigned short* __restrict__ hd,      // [5][1024][128][512]
    const unsigned short* __restrict__ zbuf, // [128][512] zeros
    unsigned int* __restrict__ flags,     // [6][1024][32]
    const float* __restrict__ boutp,
    float* __restrict__ outp)
{
  extern __shared__ char smem[];
  const int tid = threadIdx.x;
  const int lane = tid & 63;
  const int w = tid >> 6;
  const int l15 = lane & 15;
  const int l4 = lane >> 4;
  const int bid = blockIdx.x;
  const int role = bid & 7;      // XCD-grouping swizzle (perf-only)
  const int idx = bid >> 3;

  POLLDEF

  if (role < 5) {
    const int l = role;
    const int wgi = idx;          // 0..31
    const int K = (l == 0) ? 640 : 1024;
    const int nkit = K >> 5;
    const unsigned short* Wg = (l == 0) ? W0 : (l == 1) ? W1 : (l == 2) ? W2
                              : (l == 3) ? W3 : W4;
    const int row0 = wgi * 64;

    for (int mf = 0; mf < 4; ++mf)
      for (int kit = w; kit < nkit; kit += 4) {
        const s16x8 v = *reinterpret_cast<const s16x8*>(
            Wg + (size_t)(row0 + mf * 16 + l15) * K + kit * 32 + l4 * 8);
        *reinterpret_cast<s16x8*>(smem + ((mf * nkit + kit) << 10) + lane * 16) = v;
      }
    __syncthreads();

    float4 b4m[4];
    #pragma unroll
    for (int mf = 0; mf < 4; ++mf)
      b4m[mf] = *(const float4*)(bias + l * 2048 + row0 + mf * 16 + l4 * 4);

    float c_reg[4][2] = {};
    s16x8 bq[16][2];
    unsigned short* stage = (unsigned short*)(smem + STAGE_OFF);
    const int sb = w * 32 + (lane >> 1);
    const int sh = lane & 1;

    for (int t = 0; t < TT; ++t) {
      const unsigned short* hin =
          (l > 0) ? hd + (size_t)((l - 1) * TT + t) * NBH : nullptr;
      const unsigned short* hown = (t > 0) ? hd + (size_t)(l * TT + t - 1) * NBH : zbuf;
      unsigned short* hout = hd + (size_t)(l * TT + t) * NBH;

      f32x4 acc[4][2] = {};
      s16x8 xb[4][2];

      if (l == 0) {
        #pragma unroll
        for (int kx = 0; kx < 4; ++kx)
          #pragma unroll
          for (int nf = 0; nf < 2; ++nf) {
            const float* xs = x + ((size_t)(w * 32 + nf * 16 + l15) * TT + t) * 128
                              + kx * 32 + l4 * 8;
            const float4 v0 = *(const float4*)xs;
            const float4 v1 = *(const float4*)(xs + 4);
            union { s16x8 v; unsigned short a[8]; } pk;
            pk.a[0] = f2bf(v0.x); pk.a[1] = f2bf(v0.y); pk.a[2] = f2bf(v0.z); pk.a[3] = f2bf(v0.w);
            pk.a[4] = f2bf(v1.x); pk.a[5] = f2bf(v1.y); pk.a[6] = f2bf(v1.z); pk.a[7] = f2bf(v1.w);
            xb[kx][nf] = pk.v;
          }
      }

      // fused poll: lanes 0..31 = self(t-1), lanes 32..63 = prev(t)
      if (t > 0 || l > 0) {
        const unsigned int* pa;
        if (lane < 32)
          pa = (t > 0) ? FLG(l, t - 1) + lane : FLG(l - 1, t) + lane;
        else
          pa = (l > 0) ? FLG(l - 1, t) + (lane - 32) : FLG(l, t - 1) + (lane - 32);
        pollAll(pa);
      }
      // back-pressure (64-step slack, checked 1/32 steps, BEFORE load burst)
      if ((t & 31) == 0 && t >= 64) {
        const unsigned int* pa = (l < 4) ? FLG(l + 1, t - 64) + (lane & 31)
                                         : FLG(5, t - 64) + (lane & 7);
        pollAll(pa);
      }

      const unsigned short* pb0 = hown + (size_t)(w * 32 + l15) * HID2 + l4 * 8;
      const unsigned short* pb1 = pb0 + 16 * HID2;

      if (l == 0) {
        GLD2A(bq[0][0], bq[0][1], pb0, pb1, "0")    GLD2A(bq[1][0], bq[1][1], pb0, pb1, "64")
        GLD2A(bq[2][0], bq[2][1], pb0, pb1, "128")  GLD2A(bq[3][0], bq[3][1], pb0, pb1, "192")
        GLD2A(bq[4][0], bq[4][1], pb0, pb1, "256")  GLD2A(bq[5][0], bq[5][1], pb0, pb1, "320")
        GLD2A(bq[6][0], bq[6][1], pb0, pb1, "384")  GLD2A(bq[7][0], bq[7][1], pb0, pb1, "448")
        GLD2A(bq[8][0], bq[8][1], pb0, pb1, "512")  GLD2A(bq[9][0], bq[9][1], pb0, pb1, "576")
        GLD2A(bq[10][0], bq[10][1], pb0, pb1, "640") GLD2A(bq[11][0], bq[11][1], pb0, pb1, "704")
        GLD2A(bq[12][0], bq[12][1], pb0, pb1, "768") GLD2A(bq[13][0], bq[13][1], pb0, pb1, "832")
        GLD2A(bq[14][0], bq[14][1], pb0, pb1, "896") GLD2A(bq[15][0], bq[15][1], pb0, pb1, "960")
        #pragma unroll
        for (int kx = 0; kx < 4; ++kx) {
          const s16x8 a0 = LDSA(0, kx), a1 = LDSA(1, kx), a2 = LDSA(2, kx), a3 = LDSA(3, kx);
          acc[0][0] = MFM(a0, xb[kx][0], acc[0][0]); acc[0][1] = MFM(a0, xb[kx][1], acc[0][1]);
          acc[1][0] = MFM(a1, xb[kx][0], acc[1][0]); acc[1][1] = MFM(a1, xb[kx][1], acc[1][1]);
          acc[2][0] = MFM(a2, xb[kx][0], acc[2][0]); acc[2][1] = MFM(a2, xb[kx][1], acc[2][1]);
          acc[3][0] = MFM(a3, xb[kx][0], acc[3][0]); acc[3][1] = MFM(a3, xb[kx][1], acc[3][1]);
        }
        CONSUME(0, 4, "30")   CONSUME(1, 5, "28")   CONSUME(2, 6, "26")   CONSUME(3, 7, "24")
        CONSUME(4, 8, "22")   CONSUME(5, 9, "20")   CONSUME(6, 10, "18")  CONSUME(7, 11, "16")
        CONSUME(8, 12, "14")  CONSUME(9, 13, "12")  CONSUME(10, 14, "10") CONSUME(11, 15, "8")
        CONSUME(12, 16, "6")  CONSUME(13, 17, "4")  CONSUME(14, 18, "2")  CONSUME(15, 19, "0")
      } else {
        const unsigned short* qb0 = hin + (size_t)(w * 32 + l15) * HID2 + l4 * 8;
        const unsigned short* qb1 = qb0 + 16 * HID2;
        GLD2A(bq[0][0], bq[0][1], pb0, pb1, "0")    GLD2A(bq[1][0], bq[1][1], pb0, pb1, "64")
        GLD2A(bq[2][0], bq[2][1], pb0, pb1, "128")  GLD2A(bq[3][0], bq[3][1], pb0, pb1, "192")
        GLD2A(bq[4][0], bq[4][1], pb0, pb1, "256")  GLD2A(bq[5][0], bq[5][1], pb0, pb1, "320")
        GLD2A(bq[6][0], bq[6][1], pb0, pb1, "384")  GLD2A(bq[7][0], bq[7][1], pb0, pb1, "448")
        GLD2A(bq[8][0], bq[8][1], pb0, pb1, "512")  GLD2A(bq[9][0], bq[9][1], pb0, pb1, "576")
        GLD2A(bq[10][0], bq[10][1], pb0, pb1, "640") GLD2A(bq[11][0], bq[11][1], pb0, pb1, "704")
        GLD2A(bq[12][0], bq[12][1], pb0, pb1, "768") GLD2A(bq[13][0], bq[13][1], pb0, pb1, "832")
        GLD2A(bq[14][0], bq[14][1], pb0, pb1, "896") GLD2A(bq[15][0], bq[15][1], pb0, pb1, "960")
        CONSUME(0, 16, "30")  GLD2A(bq[0][0], bq[0][1], qb0, qb1, "0")
        CONSUME(1, 17, "30")  GLD2A(bq[1][0], bq[1][1], qb0, qb1, "64")
        CONSUME(2, 18, "30")  GLD2A(bq[2][0], bq[2][1], qb0, qb1, "128")
        CONSUME(3, 19, "30")  GLD2A(bq[3][0], bq[3][1], qb0, qb1, "192")
        CONSUME(4, 20, "30")  GLD2A(bq[4][0], bq[4][1], qb0, qb1, "256")
        CONSUME(5, 21, "30")  GLD2A(bq[5][0], bq[5][1], qb0, qb1, "320")
        CONSUME(6, 22, "30")  GLD2A(bq[6][0], bq[6][1], qb0, qb1, "384")
        CONSUME(7, 23, "30")  GLD2A(bq[7][0], bq[7][1], qb0, qb1, "448")
        CONSUME(8, 24, "30")  GLD2A(bq[8][0], bq[8][1], qb0, qb1, "512")
        CONSUME(9, 25, "30")  GLD2A(bq[9][0], bq[9][1], qb0, qb1, "576")
        CONSUME(10, 26, "30") GLD2A(bq[10][0], bq[10][1], qb0, qb1, "640")
        CONSUME(11, 27, "30") GLD2A(bq[11][0], bq[11][1], qb0, qb1, "704")
        CONSUME(12, 28, "30") GLD2A(bq[12][0], bq[12][1], qb0, qb1, "768")
        CONSUME(13, 29, "30") GLD2A(bq[13][0], bq[13][1], qb0, qb1, "832")
        CONSUME(14, 30, "30") GLD2A(bq[14][0], bq[14][1], qb0, qb1, "896")
        CONSUME(15, 31, "30") GLD2A(bq[15][0], bq[15][1], qb0, qb1, "960")
        CONSUME(0, 0, "30")   CONSUME(1, 1, "28")   CONSUME(2, 2, "26")  CONSUME(3, 3, "24")
        CONSUME(4, 4, "22")   CONSUME(5, 5, "20")   CONSUME(6, 6, "18")  CONSUME(7, 7, "16")
        CONSUME(8, 8, "14")   CONSUME(9, 9, "12")   CONSUME(10, 10, "10") CONSUME(11, 11, "8")
        CONSUME(12, 12, "6")  CONSUME(13, 13, "4")  CONSUME(14, 14, "2") CONSUME(15, 15, "0")
      }

      // epilogue: c in regs; h -> LDS transpose stage -> one dwordx4 system store
      #pragma unroll
      for (int mf = 0; mf < 4; ++mf) {
        #pragma unroll
        for (int nf = 0; nf < 2; ++nf) {
          const float gi = acc[mf][nf][0] + b4m[mf].x;
          const float gf = acc[mf][nf][1] + b4m[mf].y;
          const float gg = acc[mf][nf][2] + b4m[mf].z;
          const float go = acc[mf][nf][3] + b4m[mf].w;
          const float cn = sigm(gf) * c_reg[mf][nf] + sigm(gi) * tanhfast(gg);
          c_reg[mf][nf] = cn;
          stage[(w * 32 + nf * 16 + l15) * 16 + mf * 4 + l4] =
              f2bf(sigm(go) * tanhfast(cn));
        }
      }
      asm volatile("s_waitcnt lgkmcnt(0)" ::: "memory");
      __builtin_amdgcn_sched_barrier(0);
      {
        const s16x8 hvv = *reinterpret_cast<const s16x8*>(
            (const char*)stage + sb * 32 + sh * 16);
        const unsigned short* ha = hout + (size_t)sb * HID2 + wgi * 16 + sh * 8;
        asm volatile("global_store_dwordx4 %0, %1, off sc0 sc1"
                     :: "v"(ha), "v"(hvv) : "memory");
      }
      asm volatile("s_waitcnt vmcnt(0)" ::: "memory");
      __syncthreads();
      if (tid == 0) {
        const unsigned int* fa = FLG(l, t) + wgi;
        asm volatile("global_store_dword %0, %1, off sc0 sc1" :: "v"(fa), "v"(1u) : "memory");
      }
    }
  } else if (role == 5 && idx < 8) {
    // ---------------- projection ----------------
    const int wgp = idx;
    const int b0 = wgp * 16;
    for (int mf = 0; mf < 2; ++mf)
      for (int kit = 0; kit < 16; ++kit) {
        const s16x8 v = *reinterpret_cast<const s16x8*>(
            Woutb + (size_t)(w * 32 + mf * 16 + l15) * 512 + kit * 32 + l4 * 8);
        *reinterpret_cast<s16x8*>(smem + (((w * 2 + mf) * 16 + kit) << 10) + lane * 16) = v;
      }
    __syncthreads();
    float4 bo[2];
    #pragma unroll
    for (int mf = 0; mf < 2; ++mf)
      bo[mf] = *(const float4*)(boutp + w * 32 + mf * 16 + l4 * 4);

    s16x8 br[16];
    for (int t = 0; t < TT; ++t) {
      pollAll(FLG(4, t) + (lane & 31));
      const unsigned short* h4 = hd + (size_t)(4 * TT + t) * NBH;
      const unsigned short* hb = h4 + (size_t)(b0 + l15) * HID2 + l4 * 8;
      GLD1A(br[0], hb, "0")    GLD1A(br[1], hb, "64")   GLD1A(br[2], hb, "128")  GLD1A(br[3], hb, "192")
      GLD1A(br[4], hb, "256")  GLD1A(br[5], hb, "320")  GLD1A(br[6], hb, "384")  GLD1A(br[7], hb, "448")
      GLD1A(br[8], hb, "512")  GLD1A(br[9], hb, "576")  GLD1A(br[10], hb, "640") GLD1A(br[11], hb, "704")
      GLD1A(br[12], hb, "768") GLD1A(br[13], hb, "832") GLD1A(br[14], hb, "896") GLD1A(br[15], hb, "960")
      f32x4 acc2[2] = {};
      #define PCON(Q, VM)                                                        \
        {                                                                        \
          BW1(br[Q], VM);                                                        \
          const s16x8 a0 = *reinterpret_cast<const s16x8*>(                      \
              smem + (((w * 2 + 0) * 16 + Q) << 10) + lane * 16);                \
          const s16x8 a1 = *reinterpret_cast<const s16x8*>(                      \
              smem + (((w * 2 + 1) * 16 + Q) << 10) + lane * 16);                \
          acc2[0] = MFM(a0, br[Q], acc2[0]);                                     \
          acc2[1] = MFM(a1, br[Q], acc2[1]);                                     \
        }
      PCON(0, "15")  PCON(1, "14")  PCON(2, "13")  PCON(3, "12")
      PCON(4, "11")  PCON(5, "10")  PCON(6, "9")   PCON(7, "8")
      PCON(8, "7")   PCON(9, "6")   PCON(10, "5")  PCON(11, "4")
      PCON(12, "3")  PCON(13, "2")  PCON(14, "1")  PCON(15, "0")
      #pragma unroll
      for (int mf = 0; mf < 2; ++mf) {
        const int d0 = w * 32 + mf * 16 + l4 * 4;
        float4 r;
        r.x = acc2[mf][0] + bo[mf].x;
        r.y = acc2[mf][1] + bo[mf].y;
        r.z = acc2[mf][2] + bo[mf].z;
        r.w = acc2[mf][3] + bo[mf].w;
        *(float4*)(outp + ((size_t)(b0 + l15) * TT + t) * 128 + d0) = r;
      }
      asm volatile("s_waitcnt vmcnt(0)" ::: "memory");
      __syncthreads();
      if (tid == 0) {
        const unsigned int* fa = FLG(5, t) + wgp;
        asm volatile("global_store_dword %0, %1, off sc0 sc1" :: "v"(fa), "v"(1u) : "memory");
      }
    }
  }
}

// ==================== SHALLOW fallback (r4, offsets fixed) ====================
__global__ __launch_bounds__(256, 1) void lstm_persist(
    const float* __restrict__ x,
    const unsigned short* __restrict__ W0, const unsigned short* __restrict__ W1,
    const unsigned short* __restrict__ W2, const unsigned short* __restrict__ W3,
    const unsigned short* __restrict__ W4,
    const unsigned short* __restrict__ Woutb,
    const float* __restrict__ bias,
    unsigned short* __restrict__ hring,
    unsigned int* __restrict__ flags,
    const float* __restrict__ boutp,
    float* __restrict__ outp)
{
  extern __shared__ char smem[];
  const int tid = threadIdx.x;
  const int lane = tid & 63;
  const int w = tid >> 6;
  const int l15 = lane & 15;
  const int l4 = lane >> 4;
  const int bid = blockIdx.x;

  POLLDEF

  if (bid < 160) {
    const int l = bid >> 5;
    const int wgi = bid & 31;
    const int K = (l == 0) ? 640 : 1024;
    const int nkit = K >> 5;
    const unsigned short* Wg = (l == 0) ? W0 : (l == 1) ? W1 : (l == 2) ? W2
                              : (l == 3) ? W3 : W4;
    const int row0 = wgi * 64;

    for (int mf = 0; mf < 4; ++mf)
      for (int kit = w; kit < nkit; kit += 4) {
        const s16x8 v = *reinterpret_cast<const s16x8*>(
            Wg + (size_t)(row0 + mf * 16 + l15) * K + kit * 32 + l4 * 8);
        *reinterpret_cast<s16x8*>(smem + ((mf * nkit + kit) << 10) + lane * 16) = v;
      }
    __syncthreads();

    float4 b4m[4];
    #pragma unroll
    for (int mf = 0; mf < 4; ++mf)
      b4m[mf] = *(const float4*)(bias + l * 2048 + row0 + mf * 16 + l4 * 4);

    float c_reg[4][2] = {};
    s16x8 bq[16][2];
    unsigned short* stage = (unsigned short*)(smem + STAGE_OFF);
    const int sb = w * 32 + (lane >> 1);
    const int sh = lane & 1;

    for (int t = 0; t < TT; ++t) {
      const unsigned short* hin =
          (l > 0) ? hring + (size_t)((l - 1) * RING + (t & 7)) * NBH : nullptr;
      const unsigned short* hown = hring + (size_t)(l * RING + ((t + 7) & 7)) * NBH;
      unsigned short* hout = hring + (size_t)(l * RING + (t & 7)) * NBH;

      f32x4 acc[4][2] = {};
      s16x8 xb[4][2];

      if (l == 0) {
        #pragma unroll
        for (int kx = 0; kx < 4; ++kx)
          #pragma unroll
          for (int nf = 0; nf < 2; ++nf) {
            const float* xs = x + ((size_t)(w * 32 + nf * 16 + l15) * TT + t) * 128
                              + kx * 32 + l4 * 8;
            const float4 v0 = *(const float4*)xs;
            const float4 v1 = *(const float4*)(xs + 4);
            union { s16x8 v; unsigned short a[8]; } pk;
            pk.a[0] = f2bf(v0.x); pk.a[1] = f2bf(v0.y); pk.a[2] = f2bf(v0.z); pk.a[3] = f2bf(v0.w);
            pk.a[4] = f2bf(v1.x); pk.a[5] = f2bf(v1.y); pk.a[6] = f2bf(v1.z); pk.a[7] = f2bf(v1.w);
            xb[kx][nf] = pk.v;
          }
      }

      if (t > 0 || l > 0) {
        const unsigned int* pa;
        if (lane < 32)
          pa = (t > 0) ? FLG(l, t - 1) + lane : FLG(l - 1, t) + lane;
        else
          pa = (l > 0) ? FLG(l - 1, t) + (lane - 32) : FLG(l, t - 1) + (lane - 32);
        pollAll(pa);
      }
      if (t >= RING) {
        const unsigned int* pa = (l < 4) ? FLG(l + 1, t - RING) + (lane & 31)
                                         : FLG(5, t - RING) + (lane & 7);
        pollAll(pa);
      }

      const unsigned short* pb0 = hown + (size_t)(w * 32 + l15) * HID2 + l4 * 8;
      const unsigned short* pb1 = pb0 + 16 * HID2;

      if (l == 0) {
        GLD2(bq[0][0], bq[0][1], pb0, pb1, "0")    GLD2(bq[1][0], bq[1][1], pb0, pb1, "64")
        GLD2(bq[2][0], bq[2][1], pb0, pb1, "128")  GLD2(bq[3][0], bq[3][1], pb0, pb1, "192")
        GLD2(bq[4][0], bq[4][1], pb0, pb1, "256")  GLD2(bq[5][0], bq[5][1], pb0, pb1, "320")
        GLD2(bq[6][0], bq[6][1], pb0, pb1, "384")  GLD2(bq[7][0], bq[7][1], pb0, pb1, "448")
        GLD2(bq[8][0], bq[8][1], pb0, pb1, "512")  GLD2(bq[9][0], bq[9][1], pb0, pb1, "576")
        GLD2(bq[10][0], bq[10][1], pb0, pb1, "640") GLD2(bq[11][0], bq[11][1], pb0, pb1, "704")
        GLD2(bq[12][0], bq[12][1], pb0, pb1, "768") GLD2(bq[13][0], bq[13][1], pb0, pb1, "832")
        GLD2(bq[14][0], bq[14][1], pb0, pb1, "896") GLD2(bq[15][0], bq[15][1], pb0, pb1, "960")
        #pragma unroll
        for (int kx = 0; kx < 4; ++kx) {
          const s16x8 a0 = LDSA(0, kx), a1 = LDSA(1, kx), a2 = LDSA(2, kx), a3 = LDSA(3, kx);
          acc[0][0] = MFM(a0, xb[kx][0], acc[0][0]); acc[0][1] = MFM(a0, xb[kx][1], acc[0][1]);
          acc[1][0] = MFM(a1, xb[kx][0], acc[1][0]); acc[1][1] = MFM(a1, xb[kx][1], acc[1][1]);
          acc[2][0] = MFM(a2, xb[kx][0], acc[2][0]); acc[2][1] = MFM(a2, xb[kx][1], acc[2][1]);
          acc[3][0] = MFM(a3, xb[kx][0], acc[3][0]); acc[3][1] = MFM(a3, xb[kx][1], acc[3][1]);
        }
        CONSUME(0, 4, "30")   CONSUME(1, 5, "28")   CONSUME(2, 6, "26")   CONSUME(3, 7, "24")
        CONSUME(4, 8, "22")   CONSUME(5, 9, "20")   CONSUME(6, 10, "18")  CONSUME(7, 11, "16")
        CONSUME(8, 12, "14")  CONSUME(9, 13, "12")  CONSUME(10, 14, "10") CONSUME(11, 15, "8")
        CONSUME(12, 16, "6")  CONSUME(13, 17, "4")  CONSUME(14, 18, "2")  CONSUME(15, 19, "0")
      } else {
        const unsigned short* qb0 = hin + (size_t)(w * 32 + l15) * HID2 + l4 * 8;
        const unsigned short* qb1 = qb0 + 16 * HID2;
        GLD2(bq[0][0], bq[0][1], pb0, pb1, "0")    GLD2(bq[1][0], bq[1][1], pb0, pb1, "64")
        GLD2(bq[2][0], bq[2][1], pb0, pb1, "128")  GLD2(bq[3][0], bq[3][1], pb0, pb1, "192")
        GLD2(bq[4][0], bq[4][1], pb0, pb1, "256")  GLD2(bq[5][0], bq[5][1], pb0, pb1, "320")
        GLD2(bq[6][0], bq[6][1], pb0, pb1, "384")  GLD2(bq[7][0], bq[7][1], pb0, pb1, "448")
        GLD2(bq[8][0], bq[8][1], pb0, pb1, "512")  GLD2(bq[9][0], bq[9][1], pb0, pb1, "576")
        GLD2(bq[10][0], bq[10][1], pb0, pb1, "640") GLD2(bq[11][0], bq[11][1], pb0, pb1, "704")
        GLD2(bq[12][0], bq[12][1], pb0, pb1, "768") GLD2(bq[13][0], bq[13][1], pb0, pb1, "832")
        GLD2(bq[14][0], bq[14][1], pb0, pb1, "896") GLD2(bq[15][0], bq[15][1], pb0, pb1, "960")
        CONSUME(0, 16, "30")  GLD2(bq[0][0], bq[0][1], qb0, qb1, "0")
        CONSUME(1, 17, "30")  GLD2(bq[1][0], bq[1][1], qb0, qb1, "64")
        CONSUME(2, 18, "30")  GLD2(bq[2][0], bq[2][1], qb0, qb1, "128")
        CONSUME(3, 19, "30")  GLD2(bq[3][0], bq[3][1], qb0, qb1, "192")
        CONSUME(4, 20, "30")  GLD2(bq[4][0], bq[4][1], qb0, qb1, "256")
        CONSUME(5, 21, "30")  GLD2(bq[5][0], bq[5][1], qb0, qb1, "320")
        CONSUME(6, 22, "30")  GLD2(bq[6][0], bq[6][1], qb0, qb1, "384")
        CONSUME(7, 23, "30")  GLD2(bq[7][0], bq[7][1], qb0, qb1, "448")
        CONSUME(8, 24, "30")  GLD2(bq[8][0], bq[8][1], qb0, qb1, "512")
        CONSUME(9, 25, "30")  GLD2(bq[9][0], bq[9][1], qb0, qb1, "576")
        CONSUME(10, 26, "30") GLD2(bq[10][0], bq[10][1], qb0, qb1, "640")
        CONSUME(11, 27, "30") GLD2(bq[11][0], bq[11][1], qb0, qb1, "704")
        CONSUME(12, 28, "30") GLD2(bq[12][0], bq[12][1], qb0, qb1, "768")
        CONSUME(13, 29, "30") GLD2(bq[13][0], bq[13][1], qb0, qb1, "832")
        CONSUME(14, 30, "30") GLD2(bq[14][0], bq[14][1], qb0, qb1, "896")
        CONSUME(15, 31, "30") GLD2(bq[15][0], bq[15][1], qb0, qb1, "960")
        CONSUME(0, 0, "30")   CONSUME(1, 1, "28")   CONSUME(2, 2, "26")  CONSUME(3, 3, "24")
        CONSUME(4, 4, "22")   CONSUME(5, 5, "20")   CONSUME(6, 6, "18")  CONSUME(7, 7, "16")
        CONSUME(8, 8, "14")   CONSUME(9, 9, "12")   CONSUME(10, 10, "10") CONSUME(11, 11, "8")
        CONSUME(12, 12, "6")  CONSUME(13, 13, "4")  CONSUME(14, 14, "2") CONSUME(15, 15, "0")
      }

      #pragma unroll
      for (int mf = 0; mf < 4; ++mf) {
        #pragma unroll
        for (int nf = 0; nf < 2; ++nf) {
          const float gi = acc[mf][nf][0] + b4m[mf].x;
          const float gf = acc[mf][nf][1] + b4m[mf].y;
          const float gg = acc[mf][nf][2] + b4m[mf].z;
          const float go = acc[mf][nf][3] + b4m[mf].w;
          const float cn = sigm(gf) * c_reg[mf][nf] + sigm(gi) * tanhfast(gg);
          c_reg[mf][nf] = cn;
          stage[(w * 32 + nf * 16 + l15) * 16 + mf * 4 + l4] =
              f2bf(sigm(go) * tanhfast(cn));
        }
      }
      asm volatile("s_waitcnt lgkmcnt(0)" ::: "memory");
      __builtin_amdgcn_sched_barrier(0);
      {
        const s16x8 hvv = *reinterpret_cast<const s16x8*>(
            (const char*)stage + sb * 32 + sh * 16);
        const unsigned short* ha = hout + (size_t)sb * HID2 + wgi * 16 + sh * 8;
        asm volatile("global_store_dwordx4 %0, %1, off sc0 sc1"
                     :: "v"(ha), "v"(hvv) : "memory");
      }
      asm volatile("s_waitcnt vmcnt(0)" ::: "memory");
      __syncthreads();
      if (tid == 0) {
        const unsigned int* fa = FLG(l, t) + wgi;
        asm volatile("global_store_dword %0, %1, off sc0 sc1" :: "v"(fa), "v"(1u) : "memory");
      }
    }
  } else {
    const int wgp = bid - 160;
    const int b0 = wgp * 16;
    for (int mf = 0; mf < 2; ++mf)
      for (int kit = 0; kit < 16; ++kit) {
        const s16x8 v = *reinterpret_cast<const s16x8*>(
            Woutb + (size_t)(w * 32 + mf * 16 + l15) * 512 + kit * 32 + l4 * 8);
        *reinterpret_cast<s16x8*>(smem + (((w * 2 + mf) * 16 + kit) << 10) + lane * 16) = v;
      }
    __syncthreads();
    float4 bo[2];
    #pragma unroll
    for (int mf = 0; mf < 2; ++mf)
      bo[mf] = *(const float4*)(boutp + w * 32 + mf * 16 + l4 * 4);

    s16x8 br[16];
    for (int t = 0; t < TT; ++t) {
      pollAll(FLG(4, t) + (lane & 31));
      const unsigned short* h4 = hring + (size_t)(4 * RING + (t & 7)) * NBH;
      const unsigned short* hb = h4 + (size_t)(b0 + l15) * HID2 + l4 * 8;
      GLD1(br[0], hb, "0")    GLD1(br[1], hb, "64")   GLD1(br[2], hb, "128")  GLD1(br[3], hb, "192")
      GLD1(br[4], hb, "256")  GLD1(br[5], hb, "320")  GLD1(br[6], hb, "384")  GLD1(br[7], hb, "448")
      GLD1(br[8], hb, "512")  GLD1(br[9], hb, "576")  GLD1(br[10], hb, "640") GLD1(br[11], hb, "704")
      GLD1(br[12], hb, "768") GLD1(br[13], hb, "832") GLD1(br[14], hb, "896") GLD1(br[15], hb, "960")
      f32x4 acc2[2] = {};
      PCON(0, "15")  PCON(1, "14")  PCON(2, "13")  PCON(3, "12")
      PCON(4, "11")  PCON(5, "10")  PCON(6, "9")   PCON(7, "8")
      PCON(8, "7")   PCON(9, "6")   PCON(10, "5")  PCON(11, "4")
      PCON(12, "3")  PCON(13, "2")  PCON(14, "1")  PCON(15, "0")
      #pragma unroll
      for (int mf = 0; mf < 2; ++mf) {
        const int d0 = w * 32 + mf * 16 + l4 * 4;
        float4 r;
        r.x = acc2[mf][0] + bo[mf].x;
        r.y = acc2[mf][1] + bo[mf].y;
        r.z = acc2[mf][2] + bo[mf].z;
        r.w = acc2[mf][3] + bo[mf].w;
        *(float4*)(outp + ((size_t)(b0 + l15) * TT + t) * 128 + d0) = r;
      }
      asm volatile("s_waitcnt vmcnt(0)" ::: "memory");
      __syncthreads();
      if (tid == 0) {
        const unsigned int* fa = FLG(5, t) + wgp;
        asm volatile("global_store_dword %0, %1, off sc0 sc1" :: "v"(fa), "v"(1u) : "memory");
      }
    }
  }
}

extern "C" void kernel_launch(void* const* d_in, const int* in_sizes, int n_in,
                              void* d_out, int out_size, void* d_ws, size_t ws_size,
                              hipStream_t stream) {
  (void)in_sizes; (void)n_in; (void)out_size;
  const float* x     = (const float*)d_in[0];
  const float* Wih1  = (const float*)d_in[1];
  const float* Whh1  = (const float*)d_in[2];
  const float* bih1  = (const float*)d_in[3];
  const float* bhh1  = (const float*)d_in[4];
  const float* Wih_r = (const float*)d_in[5];
  const float* Whh_r = (const float*)d_in[6];
  const float* bih_r = (const float*)d_in[7];
  const float* bhh_r = (const float*)d_in[8];
  const float* Wout  = (const float*)d_in[9];
  const float* boutp = (const float*)d_in[10];

  char* ws = (char*)d_ws;
  const size_t o_W0   = 0;
  const size_t o_W1   = o_W0 + 2048ull * 640 * 2;
  const size_t o_W2   = o_W1 + 2048ull * 1024 * 2;
  const size_t o_W3   = o_W2 + 2048ull * 1024 * 2;
  const size_t o_W4   = o_W3 + 2048ull * 1024 * 2;
  const size_t o_Wout = o_W4 + 2048ull * 1024 * 2;
  const size_t o_bias = o_Wout + 128ull * 512 * 2;

  unsigned short* W0b  = (unsigned short*)(ws + o_W0);
  unsigned short* W1b  = (unsigned short*)(ws + o_W1);
  unsigned short* W2b  = (unsigned short*)(ws + o_W2);
  unsigned short* W3b  = (unsigned short*)(ws + o_W3);
  unsigned short* W4b  = (unsigned short*)(ws + o_W4);
  unsigned short* Wob  = (unsigned short*)(ws + o_Wout);
  float*          bias = (float*)(ws + o_bias);

  convW<<<1024, 256, 0, stream>>>(Wih1, Whh1, bih1, bhh1, W0b, bias, 128, 512);
  for (int l = 1; l <= 4; ++l) {
    unsigned short* Wd = (l == 1) ? W1b : (l == 2) ? W2b : (l == 3) ? W3b : W4b;
    convW<<<1024, 256, 0, stream>>>(Wih_r + (size_t)(l - 1) * 2048 * 512,
                                    Whh_r + (size_t)(l - 1) * 2048 * 512,
                                    bih_r + (size_t)(l - 1) * 2048,
                                    bhh_r + (size_t)(l - 1) * 2048,
                                    Wd, bias + l * 2048, 512, 512);
  }
  convO<<<64, 256, 0, stream>>>(Wout, Wob);

  // deep-mode layout
  const size_t o_zero = o_bias + 5ull * 2048 * 4;
  const size_t o_flag = o_zero + (size_t)NBH * 2;
  const size_t o_hd   = o_flag + 6ull * TT * 32 * 4;
  const size_t need   = o_hd + 5ull * TT * (size_t)NBH * 2;

  hipFuncSetAttribute((const void*)lstm_deep,
                      hipFuncAttributeMaxDynamicSharedMemorySize, 160 * 1024);
  hipFuncSetAttribute((const void*)lstm_persist,
                      hipFuncAttributeMaxDynamicSharedMemorySize, 160 * 1024);

  if (ws_size >= need) {
    unsigned short* zbuf = (unsigned short*)(ws + o_zero);
    unsigned int*   flg  = (unsigned int*)(ws + o_flag);
    unsigned short* hd   = (unsigned short*)(ws + o_hd);
    hipMemsetAsync(ws + o_zero, 0, o_hd - o_zero, stream);  // zbuf + flags
    lstm_deep<<<256, 256, 135168, stream>>>(x, W0b, W1b, W2b, W3b, W4b, Wob,
                                            bias, hd, zbuf, flg, boutp,
                                            (float*)d_out);
  } else {
    const size_t o_ring = o_bias + 5ull * 2048 * 4;
    const size_t o_flg  = o_ring + 5ull * RING * NBH * 2;
    const size_t o_end  = o_flg + 6ull * TT * 32 * 4;
    unsigned short* hrg = (unsigned short*)(ws + o_ring);
    unsigned int*   flg = (unsigned int*)(ws + o_flg);
    hipMemsetAsync(ws + o_ring, 0, o_end - o_ring, stream);
    lstm_persist<<<168, 256, 135168, stream>>>(x, W0b, W1b, W2b, W3b, W4b, Wob,
                                               bias, hrg, flg, boutp,
                                               (float*)d_out);
  }
}